// Round 18
// baseline (625.147 us; speedup 1.0000x reference)
//
#include <hip/hip_runtime.h>
#include <stdint.h>

// LSTM B=256,T=2048,D=U=64 fp32. Grid 128 WGs x 256 thr (4 waves):
// waves 0-1 = batch A, waves 2-3 = batch B (disjoint sH/sXZ).
// R18 rationale: R16 measured that a 2nd co-resident chain costs only
// +260cyc per wall-step (934 vs 675) but paid 2 waves/SIMD + 8-wave
// barrier. Here: 1 wave/SIMD (R15's proven regime), 4-wave barrier
// (R15's skew), and each wall-step advances TWO timesteps (one/batch).
// Per wave: 8 tiles = its batch's 32 units x 4 gates (16 MFMA/step,
// 2-deep, 8 indep chains). Lane (g,j) owns unit u = p*32+(g&1)*16+j;
// b-select = g&1 (1 cndmask/gate). g<2 lanes store c; g>=2 store h +
// publish sH. Everything else = R15 verbatim: replicated-A h-MFMA with
// persistent zero-C, xz per chunk via MFMA rows=timesteps into
// wave-private sXZ, xz[s+1] prefetch pre-barrier, one lgkm-only barrier
// per step, vmcnt never drained. k-map f(g,e)=g*8+e on BOTH A and B;
// C/D layout m89-verified.

#define T_STEPS 2048
#define DIM     64
#define GATES   256
#define CHUNK   16
#define NCHUNK  (T_STEPS / CHUNK)

typedef _Float16 f16;
typedef _Float16 f16x8 __attribute__((ext_vector_type(8)));
typedef float    f32x4 __attribute__((ext_vector_type(4)));

__device__ __forceinline__ void sync_lds() {
    __builtin_amdgcn_sched_barrier(0);
    asm volatile("s_waitcnt lgkmcnt(0)" ::: "memory");
    __builtin_amdgcn_sched_barrier(0);
    __builtin_amdgcn_s_barrier();
    __builtin_amdgcn_sched_barrier(0);
}

__device__ __forceinline__ float sigm(float z) {
    return __builtin_amdgcn_rcpf(1.f + __expf(-z));
}

#define MFMA16(A, B, C) __builtin_amdgcn_mfma_f32_16x16x32_f16(A, B, C, 0, 0, 0)

__device__ __forceinline__ void pack8(f16x8& d, const float4& a, const float4& b) {
    d[0]=(f16)a.x; d[1]=(f16)a.y; d[2]=(f16)a.z; d[3]=(f16)a.w;
    d[4]=(f16)b.x; d[5]=(f16)b.y; d[6]=(f16)b.z; d[7]=(f16)b.w;
}

__global__ __launch_bounds__(256, 1)
void lstm_r18_kernel(const float* __restrict__ x,
                     const float* __restrict__ Wx,
                     const float* __restrict__ Wh,
                     const float* __restrict__ bias,
                     float* __restrict__ out)
{
    __shared__ __align__(16) f16   sH[2][2][64];            // [half][pb][u]
    __shared__ __align__(16) float sXZ[2][2][CHUNK][32][4]; // [half][p][s][b*16+j][q]

    const int tid  = threadIdx.x;
    const int half = tid >> 7;         // batch within WG
    const int p    = (tid >> 6) & 1;   // wave within batch -> units p*32..+32
    const int lane = tid & 63;
    const int j    = lane & 15;
    const int g    = lane >> 4;        // k-group: k = ks*32 + g*8 + e
    const int bsel = g & 1;            // which 16-unit sub-block this lane owns
    const int u    = p * 32 + bsel * 16 + j;

    const int batch = blockIdx.x * 2 + half;
    const float* xb = x + (size_t)batch * T_STEPS * DIM;
    float* ob = out + (size_t)batch * T_STEPS * (2 * DIM);

    // ---- weight fragments: tile (q,b) covers col = q*64 + p*32 + b*16 + j
    f16x8 Bh[4][2][2], Bx[4][2][2];
    f32x4 bias4[4][2];
#pragma unroll
    for (int q = 0; q < 4; ++q)
#pragma unroll
        for (int b = 0; b < 2; ++b) {
            const int col = q * 64 + p * 32 + b * 16 + j;
            const float bb = bias[col];
            bias4[q][b][0] = bb; bias4[q][b][1] = bb;
            bias4[q][b][2] = bb; bias4[q][b][3] = bb;
#pragma unroll
            for (int ks = 0; ks < 2; ++ks)
#pragma unroll
                for (int e = 0; e < 8; ++e) {
                    const int k = ks * 32 + g * 8 + e;
                    Bh[q][b][ks][e] = (f16)Wh[k * GATES + col];
                    Bx[q][b][ks][e] = (f16)Wx[k * GATES + col];
                }
        }
    const f32x4 zero4 = {0.f, 0.f, 0.f, 0.f};

    // init h = 0 (256 threads cover sH exactly)
    sH[tid >> 7][(tid >> 6) & 1][tid & 63] = (f16)0.f;

    // ---- prefetch x chunk 0: A row = ts = j, feats g*8.. ----
    float4 x0, x1, x2, x3;
    {
        const float* xr = xb + (size_t)j * DIM + g * 8;
        x0 = *(const float4*)(xr);      x1 = *(const float4*)(xr + 4);
        x2 = *(const float4*)(xr + 32); x3 = *(const float4*)(xr + 36);
    }

    float c = 0.f;
    __syncthreads();

#pragma unroll 1
    for (int n = 0; n < NCHUNK; ++n) {
        // ---- xz chunk: z[q][b] = bias + X_chunk @ Wx (rows = 16 ts) ----
        f16x8 ax0, ax1;
        pack8(ax0, x0, x1); pack8(ax1, x2, x3);
        f32x4 z[4][2];
#pragma unroll
        for (int q = 0; q < 4; ++q)
#pragma unroll
            for (int b = 0; b < 2; ++b) {
                f32x4 a = MFMA16(ax0, Bx[q][b][0], bias4[q][b]);
                z[q][b] = MFMA16(ax1, Bx[q][b][1], a);
            }
        // scatter to wave-private sXZ: [4g+r][b*16+j] = {z[0..3][b][r]}
#pragma unroll
        for (int r = 0; r < 4; ++r)
#pragma unroll
            for (int b = 0; b < 2; ++b) {
                float4 v = {z[0][b][r], z[1][b][r], z[2][b][r], z[3][b][r]};
                *(float4*)&sXZ[half][p][4 * g + r][b * 16 + j][0] = v;
            }
        // s=0 xz read (in-wave DS program order -> consistent, no drain)
        float4 xzv = *(const float4*)&sXZ[half][p][0][bsel * 16 + j][0];

        // prefetch next chunk's x (returns during the 16 steps below)
        if (n + 1 < NCHUNK) {
            const float* xr = xb + ((size_t)(n + 1) * CHUNK + j) * DIM + g * 8;
            x0 = *(const float4*)(xr);      x1 = *(const float4*)(xr + 4);
            x2 = *(const float4*)(xr + 32); x3 = *(const float4*)(xr + 36);
        }

        float* obn = ob + (size_t)n * CHUNK * 128;

#pragma unroll
        for (int s = 0; s < CHUNK; ++s) {
            const int pb = s & 1;
            // A-reads FIRST post-barrier (full h of this batch)
            f16x8 A0 = *(const f16x8*)&sH[half][pb][g * 8];
            f16x8 A1 = *(const f16x8*)&sH[half][pb][32 + g * 8];

            // h @ Wh: 8 tiles, zero-C, 2-deep
            f32x4 hv[4][2];
#pragma unroll
            for (int q = 0; q < 4; ++q)
#pragma unroll
                for (int b = 0; b < 2; ++b) {
                    f32x4 a = MFMA16(A0, Bh[q][b][0], zero4);
                    hv[q][b] = MFMA16(A1, Bh[q][b][1], a);
                }

            // z for this lane's unit: b-select via g&1 (replicated rows)
            float zi = (bsel ? hv[0][1][0] : hv[0][0][0]) + xzv.x;
            float zf = (bsel ? hv[1][1][0] : hv[1][0][0]) + xzv.y;
            float zg = (bsel ? hv[2][1][0] : hv[2][0][0]) + xzv.z;
            float zo = (bsel ? hv[3][1][0] : hv[3][0][0]) + xzv.w;

            float gi = sigm(zi), gf = sigm(zf), go = sigm(zo);
            float gg = fmaf(2.f, sigm(zg + zg), -1.f);
            c = fmaf(gf, c, gi * gg);
            float e2 = __expf(-2.f * fabsf(c));
            float th = copysignf(
                fmaf(-2.f, e2 * __builtin_amdgcn_rcpf(1.f + e2), 1.f), c);
            float hh = go * th;

            // next step's xz prefetch (wave-private, stable; s=15 discarded)
            float4 xzn = *(const float4*)
                &sXZ[half][p][(s + 1) & 15][bsel * 16 + j][0];

            if (g < 2) {
                obn[s * 128 + u] = c;                    // cell out
            } else {
                sH[half][pb ^ 1][u] = (f16)hh;           // next-step h
                obn[s * 128 + 64 + u] = hh;              // hidden out
            }
            sync_lds();
            xzv = xzn;
        }
    }
}

extern "C" void kernel_launch(void* const* d_in, const int* in_sizes, int n_in,
                              void* d_out, int out_size, void* d_ws, size_t ws_size,
                              hipStream_t stream) {
    const float* x  = (const float*)d_in[0];
    const float* Wx = (const float*)d_in[1];
    const float* Wh = (const float*)d_in[2];
    const float* b  = (const float*)d_in[3];
    float* out = (float*)d_out;

    hipLaunchKernelGGL(lstm_r18_kernel, dim3(128), dim3(256), 0, stream,
                       x, Wx, Wh, b, out);
}